// Round 7
// baseline (164.625 us; speedup 1.0000x reference)
//
#include <hip/hip_runtime.h>
#include <hip/hip_bf16.h>

typedef __attribute__((ext_vector_type(8))) short short8;
typedef __attribute__((ext_vector_type(4))) float f32x4;
typedef __attribute__((ext_vector_type(2))) float f32x2;
typedef __attribute__((ext_vector_type(8))) float f32x8;

constexpr int BATCH  = 4;
constexpr int NSRC   = 2048;
constexpr int NTGT   = 8192;
constexpr int C_IN   = 256;
constexpr int C_SKIP = 128;
constexpr int DIN    = 384;   // C_IN + C_SKIP
constexpr int HID    = 256;
constexpr int MROWS  = BATCH * NTGT;  // 32768

constexpr int TGT_PER_BLK = 16;
constexpr int KNN_BLOCKS  = MROWS / TGT_PER_BLK;  // 2048
constexpr int WT_BLOCKS   = 8;                    // W1 transpose helper blocks

// ================= fused KNN + interpolate + concat (+W1 transpose, +stats zero) =================
// 512 thr: 16 targets/block, 32 lanes/target; scan processes 2 sources/iter with packed-f32 math.
__global__ __launch_bounds__(512, 4) void knn_h_kernel(const float* __restrict__ pos,
                                                       const float* __restrict__ pos_skip,
                                                       const float* __restrict__ x,
                                                       const float* __restrict__ xs,
                                                       const float* __restrict__ W1,
                                                       __hip_bfloat16* __restrict__ W1T,
                                                       __hip_bfloat16* __restrict__ H0,
                                                       float* __restrict__ stats) {
#pragma clang fp contract(off)
    const int blk = blockIdx.x;
    if (blk >= KNN_BLOCKS) {
        const int e = blk - KNN_BLOCKS;
        if (e < WT_BLOCKS) {
            const int r  = e * 32 + (threadIdx.x >> 4);  // W1T row (output channel), 32 rows/block
            const int c0 = threadIdx.x & 15;
#pragma unroll
            for (int k = 0; k < DIN / 16; ++k) {
                int c = c0 + k * 16;
                W1T[(size_t)r * DIN + c] = __float2bfloat16(W1[(size_t)c * HID + r]);
            }
        } else {
            for (int i = threadIdx.x; i < 4 * HID; i += 512) stats[i] = 0.0f;
        }
        return;
    }
    __shared__ float4 sp[NSRC];
    __shared__ float  sd[TGT_PER_BLK][3];
    __shared__ int    si[TGT_PER_BLK][3];
    const int t0 = blk * TGT_PER_BLK;
    const int b  = t0 / NTGT;
    const float* ps = pos + (size_t)b * NSRC * 3;
    for (int j = threadIdx.x; j < NSRC; j += 512) {
        float X = ps[j * 3 + 0], Y = ps[j * 3 + 1], Z = ps[j * 3 + 2];
        float s2 = ((X * X) + (Y * Y)) + (Z * Z);
        sp[j] = make_float4(X, Y, Z, s2);
    }
    __syncthreads();
    const int g  = threadIdx.x >> 5;   // target group 0..15
    const int s  = threadIdx.x & 31;   // sub-lane 0..31
    const int tr = t0 + g;
    const float px = pos_skip[tr * 3 + 0], py = pos_skip[tr * 3 + 1], pz = pos_skip[tr * 3 + 2];
    const float pt2 = ((px * px) + (py * py)) + (pz * pz);
    const f32x2 px2 = {px, px}, py2 = {py, py}, pz2 = {pz, pz}, ptv = {pt2, pt2};
    float bd0 = 3e38f, bd1 = 3e38f, bd2 = 3e38f;
    int   bi0 = 0x7fffffff, bi1 = 0x7fffffff, bi2 = 0x7fffffff;
#pragma unroll 4
    for (int k = 0; k < NSRC / 64; ++k) {
        const int j1 = k * 64 + s;        // within-lane visit order is increasing j
        const int j2 = j1 + 32;
        float4 sa = sp[j1];
        float4 sb = sp[j2];
        f32x2 vx = {sa.x, sb.x}, vy = {sa.y, sb.y}, vz = {sa.z, sb.z}, vw = {sa.w, sb.w};
        // exact replica of reference's expanded formula: (pt2 + ps2) - 2*dot, contract(off) => no FMA
        f32x2 dot = ((px2 * vx) + (py2 * vy)) + (pz2 * vz);
        f32x2 d2v = (ptv + vw) - (f32x2{2.0f, 2.0f} * dot);
#pragma unroll
        for (int h = 0; h < 2; ++h) {
            float d2 = h == 0 ? d2v.x : d2v.y;
            int   j  = h == 0 ? j1 : j2;
            bool c0 = d2 < bd0, c1 = d2 < bd1, c2 = d2 < bd2;
            bd2 = c1 ? bd1 : (c2 ? d2 : bd2);  bi2 = c1 ? bi1 : (c2 ? j : bi2);
            bd1 = c0 ? bd0 : (c1 ? d2 : bd1);  bi1 = c0 ? bi0 : (c1 ? j : bi1);
            bd0 = c0 ? d2  : bd0;              bi0 = c0 ? j  : bi0;
        }
    }
    // butterfly merge across 32 sub-lanes; lex (d, idx) preserves reference tie-break
#pragma unroll
    for (int m = 1; m <= 16; m <<= 1) {
        float od0 = __shfl_xor(bd0, m), od1 = __shfl_xor(bd1, m), od2 = __shfl_xor(bd2, m);
        int   oi0 = __shfl_xor(bi0, m), oi1 = __shfl_xor(bi1, m), oi2 = __shfl_xor(bi2, m);
#pragma unroll
        for (int e = 0; e < 3; ++e) {
            float d = e == 0 ? od0 : (e == 1 ? od1 : od2);
            int   i = e == 0 ? oi0 : (e == 1 ? oi1 : oi2);
            bool c0 = (d < bd0) || (d == bd0 && i < bi0);
            bool c1 = (d < bd1) || (d == bd1 && i < bi1);
            bool c2 = (d < bd2) || (d == bd2 && i < bi2);
            bd2 = c1 ? bd1 : (c2 ? d : bd2);  bi2 = c1 ? bi1 : (c2 ? i : bi2);
            bd1 = c0 ? bd0 : (c1 ? d : bd1);  bi1 = c0 ? bi0 : (c1 ? i : bi1);
            bd0 = c0 ? d   : bd0;             bi0 = c0 ? i  : bi0;
        }
    }
    if (s == 0) {
        sd[g][0] = bd0; sd[g][1] = bd1; sd[g][2] = bd2;
        si[g][0] = bi0; si[g][1] = bi1; si[g][2] = bi2;
    }
    __syncthreads();
    // gather + concat phase: 8 waves x 2 targets, 64-lane coalesced columns
    const int w = threadIdx.x >> 6, lane = threadIdx.x & 63;
    const float* xb = x + (size_t)b * NSRC * C_IN;
#pragma unroll
    for (int u = 0; u < 2; ++u) {
        const int tt = w * 2 + u;
        const int r  = t0 + tt;
        float w0 = 1.0f / fmaxf(sd[tt][0], 1e-16f);
        float w1 = 1.0f / fmaxf(sd[tt][1], 1e-16f);
        float w2 = 1.0f / fmaxf(sd[tt][2], 1e-16f);
        float inv = 1.0f / ((w0 + w1) + w2);
        const float* f0 = xb + (size_t)si[tt][0] * C_IN;
        const float* f1 = xb + (size_t)si[tt][1] * C_IN;
        const float* f2 = xb + (size_t)si[tt][2] * C_IN;
        __hip_bfloat16* o = H0 + (size_t)r * DIN;
#pragma unroll
        for (int kk = 0; kk < 4; ++kk) {
            int c = lane + kk * 64;
            float v = ((w0 * f0[c] + w1 * f1[c]) + w2 * f2[c]) * inv;
            o[c] = __float2bfloat16(v);
        }
        const float* srow = xs + (size_t)r * C_SKIP;
#pragma unroll
        for (int kk = 0; kk < 2; ++kk) {
            int c = lane + kk * 64;
            o[C_IN + c] = __float2bfloat16(srow[c]);
        }
    }
}

// ================= GEMM: out = relu(A@W + bias) (bf16), plus column sum/sumsq =================
// A: [MROWS][K] bf16; WT: [HID][K] bf16. 64-row x 256-col tile, 512 blocks = 2 blocks/CU
// (R6 flaw: 256 blocks = 1/CU -> barrier drains had no co-resident waves to hide under).
// A staged via global_load_lds width=16 (async, no VGPR round-trip) into [64][64] LDS with
// XOR chunk swizzle c^(row&7): BK=64 -> row stride 128 B = full bank cycle -> ds_read ~2-way (free).
// acc[2][8] = 64 VGPR; total ~140 -> 8 waves/CU.
template <int K>
__global__ __launch_bounds__(256, 2) void gemm_kernel(const __hip_bfloat16* __restrict__ A,
                                                      const __hip_bfloat16* __restrict__ WT,
                                                      const float* __restrict__ bias,
                                                      __hip_bfloat16* __restrict__ outp,
                                                      float* __restrict__ colsum,
                                                      float* __restrict__ colsq) {
    __shared__ short As[64 * 64];   // [row][64 kcols] bf16, chunk-swizzled, 8 KB
    const int t = threadIdx.x;
    const int m0 = blockIdx.x * 64;
    const int wid = t >> 6, lane = t & 63;
    const int wr = wid & 1, wcq = wid >> 1;   // row half (32 rows), col half (128 cols)
    const int l15 = lane & 15, l4 = lane >> 4;
    // staging: wave w stages rows w*8..w*8+7 (call 0) and +32 (call 1); lane -> (row, chunk)
    const int srow  = wid * 8 + (lane >> 3);        // 0..31
    const int schunk = lane & 7;
    const int scol  = (schunk ^ (srow & 7)) * 8;    // swizzled global chunk ((srow+32)&7 == srow&7)
    const short* Ash = (const short*)A;
    const short* Wsh = (const short*)WT;
    f32x4 acc[2][8] = {};
    for (int kt = 0; kt < K / 64; ++kt) {
        __syncthreads();   // previous iter's ds_reads complete before overwrite
        __builtin_amdgcn_global_load_lds(
            (const __attribute__((address_space(1))) void*)(Ash + (size_t)(m0 + srow) * K + kt * 64 + scol),
            (__attribute__((address_space(3))) void*)(As + wid * 512),
            16, 0, 0);
        __builtin_amdgcn_global_load_lds(
            (const __attribute__((address_space(1))) void*)(Ash + (size_t)(m0 + srow + 32) * K + kt * 64 + scol),
            (__attribute__((address_space(3))) void*)(As + 2048 + wid * 512),
            16, 0, 0);
        __syncthreads();   // drains vmcnt -> staged tile visible
#pragma unroll
        for (int kk = 0; kk < 2; ++kk) {
            short8 af[2], bfr[8];
#pragma unroll
            for (int mi = 0; mi < 2; ++mi) {
                int row = wr * 32 + mi * 16 + l15;
                int chunk = (kk * 4 + l4) ^ (row & 7);
                af[mi] = *(const short8*)(&As[row * 64 + chunk * 8]);
            }
#pragma unroll
            for (int ni = 0; ni < 8; ++ni)
                bfr[ni] = *(const short8*)(Wsh + (size_t)(wcq * 128 + ni * 16 + l15) * K + kt * 64 + kk * 32 + l4 * 8);
#pragma unroll
            for (int mi = 0; mi < 2; ++mi)
#pragma unroll
                for (int ni = 0; ni < 8; ++ni)
                    acc[mi][ni] = __builtin_amdgcn_mfma_f32_16x16x32_bf16(af[mi], bfr[ni], acc[mi][ni], 0, 0, 0);
        }
    }
    float bv[8];
    int col[8];
#pragma unroll
    for (int ni = 0; ni < 8; ++ni) {
        col[ni] = wcq * 128 + ni * 16 + l15;
        bv[ni] = bias[col[ni]];
    }
    float csum[8] = {}, csq[8] = {};
#pragma unroll
    for (int mi = 0; mi < 2; ++mi) {
#pragma unroll
        for (int r = 0; r < 4; ++r) {
            int rowg = m0 + wr * 32 + mi * 16 + l4 * 4 + r;  // D layout: row=(lane>>4)*4+reg
#pragma unroll
            for (int ni = 0; ni < 8; ++ni) {
                float v = fmaxf(acc[mi][ni][r] + bv[ni], 0.0f);
                outp[(size_t)rowg * HID + col[ni]] = __float2bfloat16(v);
                csum[ni] += v;
                csq[ni] += v * v;
            }
        }
    }
#pragma unroll
    for (int ni = 0; ni < 8; ++ni) {
        float sv = csum[ni], q = csq[ni];
        sv += __shfl_xor(sv, 16); sv += __shfl_xor(sv, 32);
        q  += __shfl_xor(q, 16);  q  += __shfl_xor(q, 32);
        if (l4 == 0) {
            atomicAdd(&colsum[col[ni]], sv);
            atomicAdd(&colsq[col[ni]], q);
        }
    }
}

// ================= finalize BN1 + fold into W2 =================
__global__ __launch_bounds__(256) void foldw2_kernel(const float* __restrict__ W2,
                                                     const float* __restrict__ b2,
                                                     const float* __restrict__ sum1,
                                                     const float* __restrict__ sq1,
                                                     const float* __restrict__ g1,
                                                     const float* __restrict__ be1,
                                                     __hip_bfloat16* __restrict__ W2T,
                                                     float* __restrict__ bias2f) {
    __shared__ float red[256];
    const int n = blockIdx.x, k = threadIdx.x;
    float mu  = sum1[k] * (1.0f / MROWS);
    float var = sq1[k] * (1.0f / MROWS) - mu * mu;
    float scv = g1[k] / sqrtf(var + 1e-5f);
    float shv = be1[k] - mu * scv;
    float v = W2[(size_t)k * HID + n];
    W2T[(size_t)n * HID + k] = __float2bfloat16(scv * v);
    red[k] = shv * v;
    __syncthreads();
    for (int s = 128; s > 0; s >>= 1) {
        if (k < s) red[k] += red[k + s];
        __syncthreads();
    }
    if (k == 0) bias2f[n] = b2[n] + red[0];
}

// ================= BN2: read h2 (bf16), apply scale/shift (computed in-block), write fp32 =================
__global__ __launch_bounds__(256) void bn2_kernel(const __hip_bfloat16* __restrict__ h2,
                                                  const float* __restrict__ sum2,
                                                  const float* __restrict__ sq2,
                                                  const float* __restrict__ g2,
                                                  const float* __restrict__ be2,
                                                  float* __restrict__ out) {
    __shared__ float lsc[HID], lsh[HID];
    {
        int c = threadIdx.x;
        float mu  = sum2[c] * (1.0f / MROWS);
        float var = sq2[c] * (1.0f / MROWS) - mu * mu;
        float scv = g2[c] / sqrtf(var + 1e-5f);
        lsc[c] = scv;
        lsh[c] = be2[c] - mu * scv;
    }
    __syncthreads();
    int idx = blockIdx.x * blockDim.x + threadIdx.x;  // 8-element chunk index
    const int total = MROWS * HID / 8;
    for (; idx < total; idx += gridDim.x * blockDim.x) {
        short8 v = *(const short8*)(h2 + (size_t)idx * 8);
        int c = (idx * 8) & (HID - 1);
        f32x8 o;   // single ext-vector, constant-indexed (R5 lesson: no cross-object ptr walks)
#pragma unroll
        for (int e = 0; e < 8; ++e) {
            float f = __uint_as_float(((unsigned)(unsigned short)v[e]) << 16);
            o[e] = lsc[c + e] * f + lsh[c + e];
        }
        *(f32x8*)(out + (size_t)idx * 8) = o;
    }
}

extern "C" void kernel_launch(void* const* d_in, const int* in_sizes, int n_in,
                              void* d_out, int out_size, void* d_ws, size_t ws_size,
                              hipStream_t stream) {
    const float* x    = (const float*)d_in[0];
    const float* pos  = (const float*)d_in[1];
    const float* xs   = (const float*)d_in[3];
    const float* poss = (const float*)d_in[4];
    const float* W1   = (const float*)d_in[6];
    const float* b1   = (const float*)d_in[7];
    const float* g1   = (const float*)d_in[8];
    const float* be1  = (const float*)d_in[9];
    const float* W2   = (const float*)d_in[10];
    const float* b2   = (const float*)d_in[11];
    const float* g2   = (const float*)d_in[12];
    const float* be2  = (const float*)d_in[13];

    char* ws = (char*)d_ws;
    size_t off = 0;
    auto alloc = [&](size_t bytes) -> void* {
        void* p = ws + off;
        off += (bytes + 255) & ~(size_t)255;
        return p;
    };
    __hip_bfloat16* W1T   = (__hip_bfloat16*)alloc((size_t)HID * DIN * 2);
    __hip_bfloat16* W2T   = (__hip_bfloat16*)alloc((size_t)HID * HID * 2);
    float*          stats = (float*)alloc(4 * HID * sizeof(float));
    float *sum1 = stats, *sq1 = stats + HID, *sum2 = stats + 2 * HID, *sq2 = stats + 3 * HID;
    float*          bias2f = (float*)alloc(HID * sizeof(float));
    __hip_bfloat16* H0 = (__hip_bfloat16*)alloc((size_t)MROWS * DIN * 2);
    __hip_bfloat16* H1 = (__hip_bfloat16*)alloc((size_t)MROWS * HID * 2);
    __hip_bfloat16* H2 = H0;  // H0 dead after gemm1; reuse for gemm2 output

    knn_h_kernel<<<KNN_BLOCKS + WT_BLOCKS + 1, 512, 0, stream>>>(pos, poss, x, xs, W1, W1T, H0, stats);
    gemm_kernel<DIN><<<MROWS / 64, 256, 0, stream>>>(H0, W1T, b1, H1, sum1, sq1);
    foldw2_kernel<<<HID, 256, 0, stream>>>(W2, b2, sum1, sq1, g1, be1, W2T, bias2f);
    gemm_kernel<HID><<<MROWS / 64, 256, 0, stream>>>(H1, W2T, bias2f, H2, sum2, sq2);
    bn2_kernel<<<1024, 256, 0, stream>>>(H2, sum2, sq2, g2, be2, (float*)d_out);
}

// Round 8
// 142.679 us; speedup vs baseline: 1.1538x; 1.1538x over previous
//
#include <hip/hip_runtime.h>
#include <hip/hip_bf16.h>

typedef __attribute__((ext_vector_type(8))) short short8;
typedef __attribute__((ext_vector_type(4))) float f32x4;
typedef __attribute__((ext_vector_type(2))) float f32x2;
typedef __attribute__((ext_vector_type(8))) float f32x8;

constexpr int BATCH  = 4;
constexpr int NSRC   = 2048;
constexpr int NTGT   = 8192;
constexpr int C_IN   = 256;
constexpr int C_SKIP = 128;
constexpr int DIN    = 384;   // C_IN + C_SKIP
constexpr int HID    = 256;
constexpr int MROWS  = BATCH * NTGT;  // 32768

constexpr int TGT_PER_BLK = 16;
constexpr int KNN_BLOCKS  = MROWS / TGT_PER_BLK;  // 2048
constexpr int WT_BLOCKS   = 8;                    // W1 transpose helper blocks
constexpr int LDS_STRIDE  = 36;                   // GEMM A-tile pad

// ================= fused KNN + interpolate + concat (+W1 transpose, +stats zero) =================
// Two-pass top-3: pass 1 tracks the 3 smallest DISTANCE VALUES via min/med3/max (4 VOP3/visit,
// no index bookkeeping); pass 2 rescans with the known cutoff a2 and runs the exact lex insert
// only on hits (~83% of wave-iters skip via execz). Selection semantics identical to reference.
__global__ __launch_bounds__(512, 4) void knn_h_kernel(const float* __restrict__ pos,
                                                       const float* __restrict__ pos_skip,
                                                       const float* __restrict__ x,
                                                       const float* __restrict__ xs,
                                                       const float* __restrict__ W1,
                                                       __hip_bfloat16* __restrict__ W1T,
                                                       __hip_bfloat16* __restrict__ H0,
                                                       float* __restrict__ stats) {
#pragma clang fp contract(off)
    const int blk = blockIdx.x;
    if (blk >= KNN_BLOCKS) {
        const int e = blk - KNN_BLOCKS;
        if (e < WT_BLOCKS) {
            const int r  = e * 32 + (threadIdx.x >> 4);
            const int c0 = threadIdx.x & 15;
#pragma unroll
            for (int k = 0; k < DIN / 16; ++k) {
                int c = c0 + k * 16;
                W1T[(size_t)r * DIN + c] = __float2bfloat16(W1[(size_t)c * HID + r]);
            }
        } else {
            for (int i = threadIdx.x; i < 4 * HID; i += 512) stats[i] = 0.0f;
        }
        return;
    }
    __shared__ float4 sp[NSRC];
    __shared__ float  sd[TGT_PER_BLK][3];
    __shared__ int    si[TGT_PER_BLK][3];
    const int t0 = blk * TGT_PER_BLK;
    const int b  = t0 / NTGT;
    const float* ps = pos + (size_t)b * NSRC * 3;
    for (int j = threadIdx.x; j < NSRC; j += 512) {
        float X = ps[j * 3 + 0], Y = ps[j * 3 + 1], Z = ps[j * 3 + 2];
        float s2 = ((X * X) + (Y * Y)) + (Z * Z);
        sp[j] = make_float4(X, Y, Z, s2);
    }
    __syncthreads();
    const int g  = threadIdx.x >> 5;   // target group 0..15
    const int s  = threadIdx.x & 31;   // sub-lane 0..31
    const int tr = t0 + g;
    const float px = pos_skip[tr * 3 + 0], py = pos_skip[tr * 3 + 1], pz = pos_skip[tr * 3 + 2];
    const float pt2 = ((px * px) + (py * py)) + (pz * pz);
    const f32x2 px2 = {px, px}, py2 = {py, py}, pz2 = {pz, pz}, ptv = {pt2, pt2};
    const f32x2 two = {2.0f, 2.0f};

    // ---- pass 1: 3 smallest distance values (multiset), no indices ----
    float a0 = 3e38f, a1 = 3e38f, a2 = 3e38f;
#pragma unroll 4
    for (int k = 0; k < NSRC / 64; ++k) {
        const int j1 = k * 64 + s;
        const int j2 = j1 + 32;
        float4 sa = sp[j1];
        float4 sb = sp[j2];
        f32x2 vx = {sa.x, sb.x}, vy = {sa.y, sb.y}, vz = {sa.z, sb.z}, vw = {sa.w, sb.w};
        // exact replica of reference's expanded formula: (pt2 + ps2) - 2*dot, contract(off) => no FMA
        f32x2 dot = ((px2 * vx) + (py2 * vy)) + (pz2 * vz);
        f32x2 d2v = (ptv + vw) - (two * dot);
#pragma unroll
        for (int h = 0; h < 2; ++h) {
            float d = h == 0 ? d2v.x : d2v.y;
            // sorted-insert (values): a0'=min(a0,d); a1'=med3(a0,a1,d); a2'=min(a2,max(a1,d))
            float n0 = fminf(a0, d);
            float n1 = __builtin_amdgcn_fmed3f(a0, a1, d);
            float n2 = fminf(a2, fmaxf(a1, d));
            a0 = n0; a1 = n1; a2 = n2;
        }
    }
    // value butterfly merge: top-3 of two sorted triples
#pragma unroll
    for (int m = 1; m <= 16; m <<= 1) {
        float oa = __shfl_xor(a0, m), ob = __shfl_xor(a1, m), oc = __shfl_xor(a2, m);
        float minb = fminf(a1, ob), maxb = fmaxf(a1, ob);
        float mina = fminf(a0, oa), maxa = fmaxf(a0, oa);
        float minc = fminf(a2, oc);
        float n0 = mina;
        float n1 = __builtin_amdgcn_fmed3f(a0, oa, minb);
        float n2 = __builtin_amdgcn_fmed3f(minb, maxa, fminf(maxb, minc));
        a0 = n0; a1 = n1; a2 = n2;
    }

    // ---- pass 2: exact index recovery, early-skip sources with d2 > a2 ----
    float bd0 = 3e38f, bd1 = 3e38f, bd2 = 3e38f;
    int   bi0 = 0x7fffffff, bi1 = 0x7fffffff, bi2 = 0x7fffffff;
    for (int k = 0; k < NSRC / 64; ++k) {
        const int j1 = k * 64 + s;
        const int j2 = j1 + 32;
        float4 sa = sp[j1];
        float4 sb = sp[j2];
        f32x2 vx = {sa.x, sb.x}, vy = {sa.y, sb.y}, vz = {sa.z, sb.z}, vw = {sa.w, sb.w};
        f32x2 dot = ((px2 * vx) + (py2 * vy)) + (pz2 * vz);
        f32x2 d2v = (ptv + vw) - (two * dot);
        // skip unless a candidate (d2 <= a2 keeps all ties); whole-wave skip via execz
        if (d2v.x <= a2 || d2v.y <= a2) {
#pragma unroll
            for (int h = 0; h < 2; ++h) {
                float d2 = h == 0 ? d2v.x : d2v.y;
                int   j  = h == 0 ? j1 : j2;
                bool c0 = d2 < bd0, c1 = d2 < bd1, c2 = d2 < bd2;
                bd2 = c1 ? bd1 : (c2 ? d2 : bd2);  bi2 = c1 ? bi1 : (c2 ? j : bi2);
                bd1 = c0 ? bd0 : (c1 ? d2 : bd1);  bi1 = c0 ? bi0 : (c1 ? j : bi1);
                bd0 = c0 ? d2  : bd0;              bi0 = c0 ? j  : bi0;
            }
        }
    }
    // lex (d, idx) butterfly merge -- preserves reference top_k smaller-index tie-break
#pragma unroll
    for (int m = 1; m <= 16; m <<= 1) {
        float od0 = __shfl_xor(bd0, m), od1 = __shfl_xor(bd1, m), od2 = __shfl_xor(bd2, m);
        int   oi0 = __shfl_xor(bi0, m), oi1 = __shfl_xor(bi1, m), oi2 = __shfl_xor(bi2, m);
#pragma unroll
        for (int e = 0; e < 3; ++e) {
            float d = e == 0 ? od0 : (e == 1 ? od1 : od2);
            int   i = e == 0 ? oi0 : (e == 1 ? oi1 : oi2);
            bool c0 = (d < bd0) || (d == bd0 && i < bi0);
            bool c1 = (d < bd1) || (d == bd1 && i < bi1);
            bool c2 = (d < bd2) || (d == bd2 && i < bi2);
            bd2 = c1 ? bd1 : (c2 ? d : bd2);  bi2 = c1 ? bi1 : (c2 ? i : bi2);
            bd1 = c0 ? bd0 : (c1 ? d : bd1);  bi1 = c0 ? bi0 : (c1 ? i : bi1);
            bd0 = c0 ? d   : bd0;             bi0 = c0 ? i  : bi0;
        }
    }
    if (s == 0) {
        sd[g][0] = bd0; sd[g][1] = bd1; sd[g][2] = bd2;
        si[g][0] = bi0; si[g][1] = bi1; si[g][2] = bi2;
    }
    __syncthreads();
    // gather + concat phase: 8 waves x 2 targets, 64-lane coalesced columns
    const int w = threadIdx.x >> 6, lane = threadIdx.x & 63;
    const float* xb = x + (size_t)b * NSRC * C_IN;
#pragma unroll
    for (int u = 0; u < 2; ++u) {
        const int tt = w * 2 + u;
        const int r  = t0 + tt;
        float w0 = 1.0f / fmaxf(sd[tt][0], 1e-16f);
        float w1 = 1.0f / fmaxf(sd[tt][1], 1e-16f);
        float w2 = 1.0f / fmaxf(sd[tt][2], 1e-16f);
        float inv = 1.0f / ((w0 + w1) + w2);
        const float* f0 = xb + (size_t)si[tt][0] * C_IN;
        const float* f1 = xb + (size_t)si[tt][1] * C_IN;
        const float* f2 = xb + (size_t)si[tt][2] * C_IN;
        __hip_bfloat16* o = H0 + (size_t)r * DIN;
#pragma unroll
        for (int kk = 0; kk < 4; ++kk) {
            int c = lane + kk * 64;
            float v = ((w0 * f0[c] + w1 * f1[c]) + w2 * f2[c]) * inv;
            o[c] = __float2bfloat16(v);
        }
        const float* srow = xs + (size_t)r * C_SKIP;
#pragma unroll
        for (int kk = 0; kk < 2; ++kk) {
            int c = lane + kk * 64;
            o[C_IN + c] = __float2bfloat16(srow[c]);
        }
    }
}

// ================= GEMM (R6-exact): out = relu(A@W + bias) (bf16), plus column sum/sumsq =================
// A: [MROWS][K] bf16; WT: [HID][K] bf16. 256 thr = 4 waves; tile = 128 rows x FULL N=256
// (A fetched once). Reg-staged global->LDS (compiler software-pipelines the staging loads across
// the barrier; R7's global_load_lds variant could not and regressed 28 us).
template <int K>
__global__ __launch_bounds__(256, 1) void gemm_kernel(const __hip_bfloat16* __restrict__ A,
                                                      const __hip_bfloat16* __restrict__ WT,
                                                      const float* __restrict__ bias,
                                                      __hip_bfloat16* __restrict__ outp,
                                                      float* __restrict__ colsum,
                                                      float* __restrict__ colsq) {
    __shared__ short As[128 * LDS_STRIDE];
    const int t = threadIdx.x;
    const int m0 = blockIdx.x * 128;
    const int wid = t >> 6, lane = t & 63;
    const int wr = wid & 1, wcq = wid >> 1;           // row half, col half
    const int l15 = lane & 15, l4 = lane >> 4;
    const int arow = t >> 1, acol8 = (t & 1) * 8;     // staging: 2 short8 per thread
    f32x4 acc[4][8] = {};
    const short* Ash = (const short*)A;
    const short* Wsh = (const short*)WT;
    for (int kt = 0; kt < K / 32; ++kt) {
        short8 v0 = *(const short8*)(Ash + (size_t)(m0 + arow) * K + kt * 32 + acol8);
        short8 v1 = *(const short8*)(Ash + (size_t)(m0 + arow) * K + kt * 32 + acol8 + 16);
        __syncthreads();
        *(short8*)(&As[arow * LDS_STRIDE + acol8]) = v0;
        *(short8*)(&As[arow * LDS_STRIDE + acol8 + 16]) = v1;
        __syncthreads();
        short8 af[4], bfr[8];
#pragma unroll
        for (int mi = 0; mi < 4; ++mi)
            af[mi] = *(const short8*)(&As[(wr * 64 + mi * 16 + l15) * LDS_STRIDE + l4 * 8]);
#pragma unroll
        for (int ni = 0; ni < 8; ++ni)
            bfr[ni] = *(const short8*)(Wsh + (size_t)(wcq * 128 + ni * 16 + l15) * K + kt * 32 + l4 * 8);
#pragma unroll
        for (int mi = 0; mi < 4; ++mi)
#pragma unroll
            for (int ni = 0; ni < 8; ++ni)
                acc[mi][ni] = __builtin_amdgcn_mfma_f32_16x16x32_bf16(af[mi], bfr[ni], acc[mi][ni], 0, 0, 0);
    }
    float bv[8];
    int col[8];
#pragma unroll
    for (int ni = 0; ni < 8; ++ni) {
        col[ni] = wcq * 128 + ni * 16 + l15;
        bv[ni] = bias[col[ni]];
    }
    float csum[8] = {}, csq[8] = {};
#pragma unroll
    for (int mi = 0; mi < 4; ++mi) {
#pragma unroll
        for (int r = 0; r < 4; ++r) {
            int rowg = m0 + wr * 64 + mi * 16 + l4 * 4 + r;  // D layout: row=(lane>>4)*4+reg
#pragma unroll
            for (int ni = 0; ni < 8; ++ni) {
                float v = fmaxf(acc[mi][ni][r] + bv[ni], 0.0f);
                outp[(size_t)rowg * HID + col[ni]] = __float2bfloat16(v);
                csum[ni] += v;
                csq[ni] += v * v;
            }
        }
    }
#pragma unroll
    for (int ni = 0; ni < 8; ++ni) {
        float sv = csum[ni], q = csq[ni];
        sv += __shfl_xor(sv, 16); sv += __shfl_xor(sv, 32);
        q  += __shfl_xor(q, 16);  q  += __shfl_xor(q, 32);
        if (l4 == 0) {
            atomicAdd(&colsum[col[ni]], sv);
            atomicAdd(&colsq[col[ni]], q);
        }
    }
}

// ================= finalize BN1 + fold into W2 =================
__global__ __launch_bounds__(256) void foldw2_kernel(const float* __restrict__ W2,
                                                     const float* __restrict__ b2,
                                                     const float* __restrict__ sum1,
                                                     const float* __restrict__ sq1,
                                                     const float* __restrict__ g1,
                                                     const float* __restrict__ be1,
                                                     __hip_bfloat16* __restrict__ W2T,
                                                     float* __restrict__ bias2f) {
    __shared__ float red[256];
    const int n = blockIdx.x, k = threadIdx.x;
    float mu  = sum1[k] * (1.0f / MROWS);
    float var = sq1[k] * (1.0f / MROWS) - mu * mu;
    float scv = g1[k] / sqrtf(var + 1e-5f);
    float shv = be1[k] - mu * scv;
    float v = W2[(size_t)k * HID + n];
    W2T[(size_t)n * HID + k] = __float2bfloat16(scv * v);
    red[k] = shv * v;
    __syncthreads();
    for (int s = 128; s > 0; s >>= 1) {
        if (k < s) red[k] += red[k + s];
        __syncthreads();
    }
    if (k == 0) bias2f[n] = b2[n] + red[0];
}

// ================= BN2: read h2 (bf16), apply scale/shift (computed in-block), write fp32 =================
__global__ __launch_bounds__(256) void bn2_kernel(const __hip_bfloat16* __restrict__ h2,
                                                  const float* __restrict__ sum2,
                                                  const float* __restrict__ sq2,
                                                  const float* __restrict__ g2,
                                                  const float* __restrict__ be2,
                                                  float* __restrict__ out) {
    __shared__ float lsc[HID], lsh[HID];
    {
        int c = threadIdx.x;
        float mu  = sum2[c] * (1.0f / MROWS);
        float var = sq2[c] * (1.0f / MROWS) - mu * mu;
        float scv = g2[c] / sqrtf(var + 1e-5f);
        lsc[c] = scv;
        lsh[c] = be2[c] - mu * scv;
    }
    __syncthreads();
    int idx = blockIdx.x * blockDim.x + threadIdx.x;  // 8-element chunk index
    const int total = MROWS * HID / 8;
    for (; idx < total; idx += gridDim.x * blockDim.x) {
        short8 v = *(const short8*)(h2 + (size_t)idx * 8);
        int c = (idx * 8) & (HID - 1);
        f32x8 o;
#pragma unroll
        for (int e = 0; e < 8; ++e) {
            float f = __uint_as_float(((unsigned)(unsigned short)v[e]) << 16);
            o[e] = lsc[c + e] * f + lsh[c + e];
        }
        *(f32x8*)(out + (size_t)idx * 8) = o;
    }
}

extern "C" void kernel_launch(void* const* d_in, const int* in_sizes, int n_in,
                              void* d_out, int out_size, void* d_ws, size_t ws_size,
                              hipStream_t stream) {
    const float* x    = (const float*)d_in[0];
    const float* pos  = (const float*)d_in[1];
    const float* xs   = (const float*)d_in[3];
    const float* poss = (const float*)d_in[4];
    const float* W1   = (const float*)d_in[6];
    const float* b1   = (const float*)d_in[7];
    const float* g1   = (const float*)d_in[8];
    const float* be1  = (const float*)d_in[9];
    const float* W2   = (const float*)d_in[10];
    const float* b2   = (const float*)d_in[11];
    const float* g2   = (const float*)d_in[12];
    const float* be2  = (const float*)d_in[13];

    char* ws = (char*)d_ws;
    size_t off = 0;
    auto alloc = [&](size_t bytes) -> void* {
        void* p = ws + off;
        off += (bytes + 255) & ~(size_t)255;
        return p;
    };
    __hip_bfloat16* W1T   = (__hip_bfloat16*)alloc((size_t)HID * DIN * 2);
    __hip_bfloat16* W2T   = (__hip_bfloat16*)alloc((size_t)HID * HID * 2);
    float*          stats = (float*)alloc(4 * HID * sizeof(float));
    float *sum1 = stats, *sq1 = stats + HID, *sum2 = stats + 2 * HID, *sq2 = stats + 3 * HID;
    float*          bias2f = (float*)alloc(HID * sizeof(float));
    __hip_bfloat16* H0 = (__hip_bfloat16*)alloc((size_t)MROWS * DIN * 2);
    __hip_bfloat16* H1 = (__hip_bfloat16*)alloc((size_t)MROWS * HID * 2);
    __hip_bfloat16* H2 = H0;  // H0 dead after gemm1; reuse for gemm2 output

    knn_h_kernel<<<KNN_BLOCKS + WT_BLOCKS + 1, 512, 0, stream>>>(pos, poss, x, xs, W1, W1T, H0, stats);
    gemm_kernel<DIN><<<MROWS / 128, 256, 0, stream>>>(H0, W1T, b1, H1, sum1, sq1);
    foldw2_kernel<<<HID, 256, 0, stream>>>(W2, b2, sum1, sq1, g1, be1, W2T, bias2f);
    gemm_kernel<HID><<<MROWS / 128, 256, 0, stream>>>(H1, W2T, bias2f, H2, sum2, sq2);
    bn2_kernel<<<1024, 256, 0, stream>>>(H2, sum2, sq2, g2, be2, (float*)d_out);
}